// Round 1
// baseline (1352.729 us; speedup 1.0000x reference)
//
#include <hip/hip_runtime.h>

#define BB 4
#define CG 8
#define HH 240
#define WW 1216
#define HW (HH*WW)
#define NPIX (BB*HW)

__device__ __forceinline__ float sampPC(const float* __restrict__ fb,
                                        const float* __restrict__ cf,
                                        int y, int x) {
    bool valid = ((unsigned)y < (unsigned)HH) && ((unsigned)x < (unsigned)WW);
    int yc = min(max(y, 0), HH - 1);
    int xc = min(max(x, 0), WW - 1);
    int idx = yc * WW + xc;
    float v = fb[idx] * cf[idx];
    return valid ? v : 0.0f;
}

__global__ __launch_bounds__(256) void conv_offaff(
    const float* __restrict__ g, const float* __restrict__ cw,
    const float* __restrict__ cb, const float* __restrict__ asc,
    float* __restrict__ out_off, float* __restrict__ out_aff,
    float* __restrict__ out_scale)
{
    int gid = blockIdx.x * 256 + threadIdx.x;
    if (gid == 0) out_scale[0] = asc[0];
    if (gid >= NPIX) return;
    int w = gid % WW;
    int tmp = gid / WW;
    int h = tmp % HH;
    int b = tmp / HH;

    float acc[24];
    #pragma unroll
    for (int o = 0; o < 24; ++o) acc[o] = cb[o];

    const float* gb = g + (size_t)b * CG * HW;
    for (int i = 0; i < CG; ++i) {
        for (int kh = 0; kh < 3; ++kh) {
            int y = h + kh - 1;
            if ((unsigned)y >= (unsigned)HH) continue;
            for (int kw = 0; kw < 3; ++kw) {
                int x = w + kw - 1;
                if ((unsigned)x >= (unsigned)WW) continue;
                float xv = gb[i * HW + y * WW + x];
                #pragma unroll
                for (int o = 0; o < 24; ++o)
                    acc[o] = fmaf(xv, cw[((o * CG + i) * 3 + kh) * 3 + kw], acc[o]);
            }
        }
    }

    int pix = h * WW + w;

    // offsets: channel 2k = y, 2k+1 = x; zero pair inserted at k=4
    #pragma unroll
    for (int k = 0; k < 9; ++k) {
        float oy, ox;
        if (k < 4)      { oy = acc[2 * k];     ox = acc[2 * k + 1]; }
        else if (k == 4){ oy = 0.0f;           ox = 0.0f; }
        else            { oy = acc[2 * k - 2]; ox = acc[2 * k - 1]; }
        out_off[(size_t)(b * 18 + 2 * k) * HW + pix]     = oy;
        out_off[(size_t)(b * 18 + 2 * k + 1) * HW + pix] = ox;
    }

    // affinities
    float inv = 1.0f / (asc[0] + 1e-8f);
    float a[8];
    float s = 0.0f;
    #pragma unroll
    for (int c = 0; c < 8; ++c) {
        a[c] = tanhf(acc[16 + c]) * inv;
        s += fabsf(a[c]);
    }
    s += 1e-4f;
    s = fmaxf(s, 1.0f);
    float sum = 0.0f;
    #pragma unroll
    for (int c = 0; c < 8; ++c) {
        a[c] = a[c] / s;
        sum += a[c];
    }
    float aref = 1.0f - sum;
    #pragma unroll
    for (int c = 0; c < 4; ++c)
        out_aff[(size_t)(b * 9 + c) * HW + pix] = a[c];
    out_aff[(size_t)(b * 9 + 4) * HW + pix] = aref;
    #pragma unroll
    for (int c = 4; c < 8; ++c)
        out_aff[(size_t)(b * 9 + c + 1) * HW + pix] = a[c];
}

__global__ __launch_bounds__(256) void prop(
    const float* __restrict__ fp, const float* __restrict__ conf,
    const float* __restrict__ off, const float* __restrict__ aff,
    float* __restrict__ fout, float* __restrict__ ffinal)
{
    int gid = blockIdx.x * 256 + threadIdx.x;
    if (gid >= NPIX) return;
    int w = gid % WW;
    int tmp = gid / WW;
    int h = tmp % HH;
    int b = tmp / HH;
    int pix = h * WW + w;

    const float* fb = fp + (size_t)b * HW;
    const float* cf = conf + (size_t)b * HW;

    float res = 0.0f;
    #pragma unroll
    for (int k = 0; k < 9; ++k) {
        float oy = off[(size_t)(b * 18 + 2 * k) * HW + pix];
        float ox = off[(size_t)(b * 18 + 2 * k + 1) * HW + pix];
        float av = aff[(size_t)(b * 9 + k) * HW + pix];

        float yy = (float)(h + k / 3 - 1) + oy;
        float xx = (float)(w + k % 3 - 1) + ox;

        float y0f = floorf(yy), x0f = floorf(xx);
        float ty = yy - y0f, tx = xx - x0f;
        int y0 = (int)y0f, x0 = (int)x0f;

        float v00 = sampPC(fb, cf, y0,     x0);
        float v01 = sampPC(fb, cf, y0,     x0 + 1);
        float v10 = sampPC(fb, cf, y0 + 1, x0);
        float v11 = sampPC(fb, cf, y0 + 1, x0 + 1);

        float sk = (1.0f - ty) * (1.0f - tx) * v00
                 + (1.0f - ty) * tx          * v01
                 + ty          * (1.0f - tx) * v10
                 + ty          * tx          * v11;
        res = fmaf(av, sk, res);
    }
    fout[gid] = res;
    if (ffinal) ffinal[gid] = res;
}

extern "C" void kernel_launch(void* const* d_in, const int* in_sizes, int n_in,
                              void* d_out, int out_size, void* d_ws, size_t ws_size,
                              hipStream_t stream) {
    const float* feat_init  = (const float*)d_in[0];
    const float* guidance   = (const float*)d_in[1];
    const float* confidence = (const float*)d_in[2];
    const float* conv_w     = (const float*)d_in[3];
    const float* conv_b     = (const float*)d_in[4];
    const float* aff_scale  = (const float*)d_in[5];

    float* out        = (float*)d_out;
    float* feat_final = out;                          // NPIX
    float* feats      = out + (size_t)NPIX;           // 18*NPIX
    float* offset     = out + (size_t)19 * NPIX;      // 18*NPIX
    float* affout     = out + (size_t)37 * NPIX;      // 9*NPIX
    float* scale_out  = out + (size_t)46 * NPIX;      // 1

    int nblocks = (NPIX + 255) / 256;

    conv_offaff<<<nblocks, 256, 0, stream>>>(guidance, conv_w, conv_b, aff_scale,
                                             offset, affout, scale_out);

    const float* prev = feat_init;
    for (int t = 0; t < 18; ++t) {
        float* cur = feats + (size_t)t * NPIX;
        prop<<<nblocks, 256, 0, stream>>>(prev, confidence, offset, affout, cur,
                                          (t == 17) ? feat_final : nullptr);
        prev = cur;
    }
}

// Round 2
// 884.628 us; speedup vs baseline: 1.5291x; 1.5291x over previous
//
#include <hip/hip_runtime.h>

#define BB 4
#define CG 8
#define HH 240
#define WW 1216
#define HW (HH*WW)
#define NPIX (BB*HW)

__device__ __forceinline__ float sampPC(const float* __restrict__ fb,
                                        const float* __restrict__ cf,
                                        int y, int x) {
    bool valid = ((unsigned)y < (unsigned)HH) && ((unsigned)x < (unsigned)WW);
    int yc = min(max(y, 0), HH - 1);
    int xc = min(max(x, 0), WW - 1);
    int idx = yc * WW + xc;
    float v = fb[idx] * cf[idx];
    return valid ? v : 0.0f;
}

__global__ __launch_bounds__(256) void conv_offaff(
    const float* __restrict__ g, const float* __restrict__ cw,
    const float* __restrict__ cb, const float* __restrict__ asc,
    float* __restrict__ out_off, float* __restrict__ out_aff,
    float* __restrict__ out_scale)
{
    int gid = blockIdx.x * 256 + threadIdx.x;
    if (gid == 0) out_scale[0] = asc[0];
    if (gid >= NPIX) return;
    int w = gid % WW;
    int tmp = gid / WW;
    int h = tmp % HH;
    int b = tmp / HH;

    float acc[24];
    #pragma unroll
    for (int o = 0; o < 24; ++o) acc[o] = cb[o];

    const float* gb = g + (size_t)b * CG * HW;
    for (int i = 0; i < CG; ++i) {
        for (int kh = 0; kh < 3; ++kh) {
            int y = h + kh - 1;
            if ((unsigned)y >= (unsigned)HH) continue;
            for (int kw = 0; kw < 3; ++kw) {
                int x = w + kw - 1;
                if ((unsigned)x >= (unsigned)WW) continue;
                float xv = gb[i * HW + y * WW + x];
                #pragma unroll
                for (int o = 0; o < 24; ++o)
                    acc[o] = fmaf(xv, cw[((o * CG + i) * 3 + kh) * 3 + kw], acc[o]);
            }
        }
    }

    int pix = h * WW + w;

    #pragma unroll
    for (int k = 0; k < 9; ++k) {
        float oy, ox;
        if (k < 4)      { oy = acc[2 * k];     ox = acc[2 * k + 1]; }
        else if (k == 4){ oy = 0.0f;           ox = 0.0f; }
        else            { oy = acc[2 * k - 2]; ox = acc[2 * k - 1]; }
        out_off[(size_t)(b * 18 + 2 * k) * HW + pix]     = oy;
        out_off[(size_t)(b * 18 + 2 * k + 1) * HW + pix] = ox;
    }

    float inv = 1.0f / (asc[0] + 1e-8f);
    float a[8];
    float s = 0.0f;
    #pragma unroll
    for (int c = 0; c < 8; ++c) {
        a[c] = tanhf(acc[16 + c]) * inv;
        s += fabsf(a[c]);
    }
    s += 1e-4f;
    s = fmaxf(s, 1.0f);
    float sum = 0.0f;
    #pragma unroll
    for (int c = 0; c < 8; ++c) {
        a[c] = a[c] / s;
        sum += a[c];
    }
    float aref = 1.0f - sum;
    #pragma unroll
    for (int c = 0; c < 4; ++c)
        out_aff[(size_t)(b * 9 + c) * HW + pix] = a[c];
    out_aff[(size_t)(b * 9 + 4) * HW + pix] = aref;
    #pragma unroll
    for (int c = 4; c < 8; ++c)
        out_aff[(size_t)(b * 9 + c + 1) * HW + pix] = a[c];
}

// ---------- precompute step-invariant bilinear taps ----------
__global__ __launch_bounds__(256) void prep_taps(
    const float* __restrict__ off, const float* __restrict__ aff,
    const float* __restrict__ feat_init, const float* __restrict__ conf,
    float4* __restrict__ w4, int* __restrict__ ipack, float* __restrict__ fc0)
{
    int gid = blockIdx.x * 256 + threadIdx.x;
    if (gid >= NPIX) return;
    int w = gid % WW;
    int tmp = gid / WW;
    int h = tmp % HH;
    int b = tmp / HH;
    int pix = h * WW + w;

    fc0[gid] = feat_init[gid] * conf[gid];

    #pragma unroll
    for (int k = 0; k < 9; ++k) {
        float oy = off[(size_t)(b * 18 + 2 * k) * HW + pix];
        float ox = off[(size_t)(b * 18 + 2 * k + 1) * HW + pix];
        float av = aff[(size_t)(b * 9 + k) * HW + pix];

        float yy = (float)(h + k / 3 - 1) + oy;
        float xx = (float)(w + k % 3 - 1) + ox;

        float y0f = floorf(yy), x0f = floorf(xx);
        float ty = yy - y0f, tx = xx - x0f;

        float vy0 = (y0f >= 0.0f && y0f <= (float)(HH - 1)) ? 1.0f : 0.0f;
        float vy1 = (y0f + 1.0f >= 0.0f && y0f + 1.0f <= (float)(HH - 1)) ? 1.0f : 0.0f;
        float vx0 = (x0f >= 0.0f && x0f <= (float)(WW - 1)) ? 1.0f : 0.0f;
        float vx1 = (x0f + 1.0f >= 0.0f && x0f + 1.0f <= (float)(WW - 1)) ? 1.0f : 0.0f;

        float4 wv;
        wv.x = av * (1.0f - ty) * (1.0f - tx) * vy0 * vx0;
        wv.y = av * (1.0f - ty) * tx          * vy0 * vx1;
        wv.z = av * ty          * (1.0f - tx) * vy1 * vx0;
        wv.w = av * ty          * tx          * vy1 * vx1;

        int y0i = (int)fminf(fmaxf(y0f, -1.0f), (float)(HH - 1));
        int x0i = (int)fminf(fmaxf(x0f, -1.0f), (float)(WW - 1));

        ipack[(size_t)k * NPIX + gid] = ((y0i + 1) << 16) | ((x0i + 1) & 0xffff);
        w4[(size_t)k * NPIX + gid] = wv;
    }
}

__global__ __launch_bounds__(256) void prop2(
    const float* __restrict__ fcIn, const float* __restrict__ conf,
    const float4* __restrict__ w4, const int* __restrict__ ipack,
    float* __restrict__ fout, float* __restrict__ fcOut, float* __restrict__ ffinal)
{
    int gid = blockIdx.x * 256 + threadIdx.x;
    if (gid >= NPIX) return;
    int b = gid / HW;
    const float* fcb = fcIn + (size_t)b * HW;

    float res = 0.0f;
    #pragma unroll
    for (int k = 0; k < 9; ++k) {
        int p = ipack[(size_t)k * NPIX + gid];
        float4 wv = w4[(size_t)k * NPIX + gid];
        int y0 = (p >> 16) - 1;
        int x0 = (p & 0xffff) - 1;
        int yA = max(y0, 0), yB = min(y0 + 1, HH - 1);
        int xA = max(x0, 0), xB = min(x0 + 1, WW - 1);
        int rA = yA * WW, rB = yB * WW;
        res = fmaf(wv.x, fcb[rA + xA], res);
        res = fmaf(wv.y, fcb[rA + xB], res);
        res = fmaf(wv.z, fcb[rB + xA], res);
        res = fmaf(wv.w, fcb[rB + xB], res);
    }
    fout[gid] = res;
    if (fcOut)  fcOut[gid]  = res * conf[gid];
    if (ffinal) ffinal[gid] = res;
}

// ---------- fallback prop (no workspace needed) ----------
__global__ __launch_bounds__(256) void prop(
    const float* __restrict__ fp, const float* __restrict__ conf,
    const float* __restrict__ off, const float* __restrict__ aff,
    float* __restrict__ fout, float* __restrict__ ffinal)
{
    int gid = blockIdx.x * 256 + threadIdx.x;
    if (gid >= NPIX) return;
    int w = gid % WW;
    int tmp = gid / WW;
    int h = tmp % HH;
    int b = tmp / HH;
    int pix = h * WW + w;

    const float* fb = fp + (size_t)b * HW;
    const float* cf = conf + (size_t)b * HW;

    float res = 0.0f;
    #pragma unroll
    for (int k = 0; k < 9; ++k) {
        float oy = off[(size_t)(b * 18 + 2 * k) * HW + pix];
        float ox = off[(size_t)(b * 18 + 2 * k + 1) * HW + pix];
        float av = aff[(size_t)(b * 9 + k) * HW + pix];

        float yy = (float)(h + k / 3 - 1) + oy;
        float xx = (float)(w + k % 3 - 1) + ox;

        float y0f = floorf(yy), x0f = floorf(xx);
        float ty = yy - y0f, tx = xx - x0f;
        int y0 = (int)y0f, x0 = (int)x0f;

        float v00 = sampPC(fb, cf, y0,     x0);
        float v01 = sampPC(fb, cf, y0,     x0 + 1);
        float v10 = sampPC(fb, cf, y0 + 1, x0);
        float v11 = sampPC(fb, cf, y0 + 1, x0 + 1);

        float sk = (1.0f - ty) * (1.0f - tx) * v00
                 + (1.0f - ty) * tx          * v01
                 + ty          * (1.0f - tx) * v10
                 + ty          * tx          * v11;
        res = fmaf(av, sk, res);
    }
    fout[gid] = res;
    if (ffinal) ffinal[gid] = res;
}

extern "C" void kernel_launch(void* const* d_in, const int* in_sizes, int n_in,
                              void* d_out, int out_size, void* d_ws, size_t ws_size,
                              hipStream_t stream) {
    const float* feat_init  = (const float*)d_in[0];
    const float* guidance   = (const float*)d_in[1];
    const float* confidence = (const float*)d_in[2];
    const float* conv_w     = (const float*)d_in[3];
    const float* conv_b     = (const float*)d_in[4];
    const float* aff_scale  = (const float*)d_in[5];

    float* out        = (float*)d_out;
    float* feat_final = out;
    float* feats      = out + (size_t)NPIX;
    float* offset     = out + (size_t)19 * NPIX;
    float* affout     = out + (size_t)37 * NPIX;
    float* scale_out  = out + (size_t)46 * NPIX;

    int nblocks = (NPIX + 255) / 256;

    conv_offaff<<<nblocks, 256, 0, stream>>>(guidance, conv_w, conv_b, aff_scale,
                                             offset, affout, scale_out);

    // workspace layout: w4 (9*NPIX float4) | ipack (9*NPIX int) | fcA | fcB
    size_t need = (size_t)9 * NPIX * 16 + (size_t)9 * NPIX * 4 + (size_t)2 * NPIX * 4;

    if (ws_size >= need) {
        char* wsb = (char*)d_ws;
        float4* w4   = (float4*)wsb;
        int*   ipack = (int*)(wsb + (size_t)9 * NPIX * 16);
        float* fcA   = (float*)(wsb + (size_t)9 * NPIX * 16 + (size_t)9 * NPIX * 4);
        float* fcB   = fcA + NPIX;

        prep_taps<<<nblocks, 256, 0, stream>>>(offset, affout, feat_init, confidence,
                                               w4, ipack, fcA);

        float* fcIn = fcA;
        float* fcOut = fcB;
        for (int t = 0; t < 18; ++t) {
            float* cur = feats + (size_t)t * NPIX;
            prop2<<<nblocks, 256, 0, stream>>>(fcIn, confidence, w4, ipack, cur,
                                               (t == 17) ? nullptr : fcOut,
                                               (t == 17) ? feat_final : nullptr);
            float* tmp = fcIn; fcIn = fcOut; fcOut = tmp;
        }
    } else {
        const float* prev = feat_init;
        for (int t = 0; t < 18; ++t) {
            float* cur = feats + (size_t)t * NPIX;
            prop<<<nblocks, 256, 0, stream>>>(prev, confidence, offset, affout, cur,
                                              (t == 17) ? feat_final : nullptr);
            prev = cur;
        }
    }
}

// Round 4
// 873.246 us; speedup vs baseline: 1.5491x; 1.0130x over previous
//
#include <hip/hip_runtime.h>

#define BB 4
#define CG 8
#define HH 240
#define WW 1216
#define HW (HH*WW)
#define NPIX (BB*HW)

// ---------------- fused conv + offsets/affinities + tap precompute ----------------
__global__ __launch_bounds__(256) void conv_fused(
    const float* __restrict__ g, const float* __restrict__ cw,
    const float* __restrict__ cb, const float* __restrict__ asc,
    const float* __restrict__ feat_init, const float* __restrict__ conf,
    float* __restrict__ out_off, float* __restrict__ out_aff,
    float* __restrict__ out_scale,
    unsigned long long* __restrict__ tp, float* __restrict__ tav,
    float* __restrict__ fc0)
{
    int gid = blockIdx.x * 256 + threadIdx.x;
    if (gid == 0) out_scale[0] = asc[0];
    if (gid >= NPIX) return;
    int w = gid % WW;
    int tmp = gid / WW;
    int h = tmp % HH;
    int b = tmp / HH;

    float acc[24];
    #pragma unroll
    for (int o = 0; o < 24; ++o) acc[o] = cb[o];

    const float* gb = g + (size_t)b * CG * HW;
    for (int i = 0; i < CG; ++i) {
        for (int kh = 0; kh < 3; ++kh) {
            int y = h + kh - 1;
            if ((unsigned)y >= (unsigned)HH) continue;
            for (int kw = 0; kw < 3; ++kw) {
                int x = w + kw - 1;
                if ((unsigned)x >= (unsigned)WW) continue;
                float xv = gb[i * HW + y * WW + x];
                #pragma unroll
                for (int o = 0; o < 24; ++o)
                    acc[o] = fmaf(xv, cw[((o * CG + i) * 3 + kh) * 3 + kw], acc[o]);
            }
        }
    }

    int pix = h * WW + w;

    // offsets per neighbor k (zero pair inserted at k=4)
    float oyk[9], oxk[9];
    #pragma unroll
    for (int k = 0; k < 9; ++k) {
        if (k < 4)       { oyk[k] = acc[2 * k];     oxk[k] = acc[2 * k + 1]; }
        else if (k == 4) { oyk[k] = 0.0f;           oxk[k] = 0.0f; }
        else             { oyk[k] = acc[2 * k - 2]; oxk[k] = acc[2 * k - 1]; }
        out_off[(size_t)(b * 18 + 2 * k) * HW + pix]     = oyk[k];
        out_off[(size_t)(b * 18 + 2 * k + 1) * HW + pix] = oxk[k];
    }

    // affinities
    float inv = 1.0f / (asc[0] + 1e-8f);
    float a[8];
    float s = 0.0f;
    #pragma unroll
    for (int c = 0; c < 8; ++c) {
        a[c] = tanhf(acc[16 + c]) * inv;
        s += fabsf(a[c]);
    }
    s += 1e-4f;
    s = fmaxf(s, 1.0f);
    float sum = 0.0f;
    #pragma unroll
    for (int c = 0; c < 8; ++c) {
        a[c] = a[c] / s;
        sum += a[c];
    }
    float a9[9];
    #pragma unroll
    for (int c = 0; c < 4; ++c) a9[c] = a[c];
    a9[4] = 1.0f - sum;
    #pragma unroll
    for (int c = 4; c < 8; ++c) a9[c + 1] = a[c];

    #pragma unroll
    for (int k = 0; k < 9; ++k)
        out_aff[(size_t)(b * 9 + k) * HW + pix] = a9[k];

    if (tp) {
        #pragma unroll
        for (int k = 0; k < 9; ++k) {
            float yy = (float)(h + k / 3 - 1) + oyk[k];
            float xx = (float)(w + k % 3 - 1) + oxk[k];
            float y0f = floorf(yy), x0f = floorf(xx);
            float ty = yy - y0f, tx = xx - x0f;

            unsigned vy0 = (y0f >= 0.0f   && y0f <= 239.0f)  ? 1u : 0u;
            unsigned vy1 = (y0f >= -1.0f  && y0f <= 238.0f)  ? 1u : 0u;
            unsigned vx0 = (x0f >= 0.0f   && x0f <= 1215.0f) ? 1u : 0u;
            unsigned vx1 = (x0f >= -1.0f  && x0f <= 1214.0f) ? 1u : 0u;

            int y0i = (int)fminf(fmaxf(y0f, -1.0f), 239.0f);
            int x0i = (int)fminf(fmaxf(x0f, -1.0f), 1215.0f);

            unsigned pack = (unsigned)(y0i + 1) | ((unsigned)(x0i + 1) << 8)
                          | (vy0 << 19) | (vy1 << 20) | (vx0 << 21) | (vx1 << 22);
            unsigned tyq = (unsigned)(fminf(ty, 0.99999f) * 65535.0f + 0.5f);
            unsigned txq = (unsigned)(fminf(tx, 0.99999f) * 65535.0f + 0.5f);
            unsigned frac = tyq | (txq << 16);

            tp[(size_t)k * NPIX + gid] =
                (unsigned long long)pack | ((unsigned long long)frac << 32);
            tav[(size_t)k * NPIX + gid] = a9[k];
        }
        fc0[gid] = feat_init[gid] * conf[gid];
    }
}

// ---------------- propagation with compressed taps ----------------
__global__ __launch_bounds__(256) void prop2(
    const float* __restrict__ fcIn, const float* __restrict__ conf,
    const unsigned long long* __restrict__ tp, const float* __restrict__ tav,
    float* __restrict__ fout, float* __restrict__ fcOut, float* __restrict__ ffinal)
{
    int gid = blockIdx.x * 256 + threadIdx.x;
    if (gid >= NPIX) return;
    int b = gid / HW;
    const float* fcb = fcIn + (size_t)b * HW;

    float res = 0.0f;
    #pragma unroll
    for (int k = 0; k < 9; ++k) {
        unsigned long long P8 = __builtin_nontemporal_load(&tp[(size_t)k * NPIX + gid]);
        float av = __builtin_nontemporal_load(&tav[(size_t)k * NPIX + gid]);

        unsigned Px = (unsigned)P8;
        unsigned Py = (unsigned)(P8 >> 32);

        int y0 = (int)(Px & 0xffu) - 1;
        int x0 = (int)((Px >> 8) & 0x7ffu) - 1;
        float ty = (float)(Py & 0xffffu) * (1.0f / 65535.0f);
        float tx = (float)(Py >> 16)     * (1.0f / 65535.0f);
        float fy0 = (Px & (1u << 19)) ? 1.0f : 0.0f;
        float fy1 = (Px & (1u << 20)) ? 1.0f : 0.0f;
        float fx0 = (Px & (1u << 21)) ? 1.0f : 0.0f;
        float fx1 = (Px & (1u << 22)) ? 1.0f : 0.0f;

        float cy0 = fy0 * (1.0f - ty), cy1 = fy1 * ty;
        float cx0 = fx0 * (1.0f - tx), cx1 = fx1 * tx;

        int yA = max(y0, 0), yB = min(y0 + 1, HH - 1);
        int xA = max(x0, 0), xB = min(x0 + 1, WW - 1);
        int rA = yA * WW, rB = yB * WW;

        float u0 = fmaf(cx1, fcb[rA + xB], cx0 * fcb[rA + xA]);
        float u1 = fmaf(cx1, fcb[rB + xB], cx0 * fcb[rB + xA]);
        res = fmaf(av, fmaf(cy1, u1, cy0 * u0), res);
    }
    __builtin_nontemporal_store(res, &fout[gid]);
    if (fcOut)  fcOut[gid] = res * conf[gid];
    if (ffinal) __builtin_nontemporal_store(res, &ffinal[gid]);
}

// ---------------- fallback prop (no workspace needed) ----------------
__device__ __forceinline__ float sampPC(const float* __restrict__ fb,
                                        const float* __restrict__ cf,
                                        int y, int x) {
    bool valid = ((unsigned)y < (unsigned)HH) && ((unsigned)x < (unsigned)WW);
    int yc = min(max(y, 0), HH - 1);
    int xc = min(max(x, 0), WW - 1);
    int idx = yc * WW + xc;
    float v = fb[idx] * cf[idx];
    return valid ? v : 0.0f;
}

__global__ __launch_bounds__(256) void prop(
    const float* __restrict__ fp, const float* __restrict__ conf,
    const float* __restrict__ off, const float* __restrict__ aff,
    float* __restrict__ fout, float* __restrict__ ffinal)
{
    int gid = blockIdx.x * 256 + threadIdx.x;
    if (gid >= NPIX) return;
    int w = gid % WW;
    int tmp = gid / WW;
    int h = tmp % HH;
    int b = tmp / HH;
    int pix = h * WW + w;

    const float* fb = fp + (size_t)b * HW;
    const float* cf = conf + (size_t)b * HW;

    float res = 0.0f;
    #pragma unroll
    for (int k = 0; k < 9; ++k) {
        float oy = off[(size_t)(b * 18 + 2 * k) * HW + pix];
        float ox = off[(size_t)(b * 18 + 2 * k + 1) * HW + pix];
        float av = aff[(size_t)(b * 9 + k) * HW + pix];

        float yy = (float)(h + k / 3 - 1) + oy;
        float xx = (float)(w + k % 3 - 1) + ox;

        float y0f = floorf(yy), x0f = floorf(xx);
        float ty = yy - y0f, tx = xx - x0f;
        int y0 = (int)y0f, x0 = (int)x0f;

        float v00 = sampPC(fb, cf, y0,     x0);
        float v01 = sampPC(fb, cf, y0,     x0 + 1);
        float v10 = sampPC(fb, cf, y0 + 1, x0);
        float v11 = sampPC(fb, cf, y0 + 1, x0 + 1);

        float sk = (1.0f - ty) * (1.0f - tx) * v00
                 + (1.0f - ty) * tx          * v01
                 + ty          * (1.0f - tx) * v10
                 + ty          * tx          * v11;
        res = fmaf(av, sk, res);
    }
    fout[gid] = res;
    if (ffinal) ffinal[gid] = res;
}

extern "C" void kernel_launch(void* const* d_in, const int* in_sizes, int n_in,
                              void* d_out, int out_size, void* d_ws, size_t ws_size,
                              hipStream_t stream) {
    const float* feat_init  = (const float*)d_in[0];
    const float* guidance   = (const float*)d_in[1];
    const float* confidence = (const float*)d_in[2];
    const float* conv_w     = (const float*)d_in[3];
    const float* conv_b     = (const float*)d_in[4];
    const float* aff_scale  = (const float*)d_in[5];

    float* out        = (float*)d_out;
    float* feat_final = out;
    float* feats      = out + (size_t)NPIX;
    float* offset     = out + (size_t)19 * NPIX;
    float* affout     = out + (size_t)37 * NPIX;
    float* scale_out  = out + (size_t)46 * NPIX;

    int nblocks = (NPIX + 255) / 256;

    // workspace layout: tp (9*NPIX u64) | tav (9*NPIX f32) | fcA | fcB
    size_t need = (size_t)9 * NPIX * 8 + (size_t)9 * NPIX * 4 + (size_t)2 * NPIX * 4;

    if (ws_size >= need) {
        char* wsb = (char*)d_ws;
        unsigned long long* tp = (unsigned long long*)wsb;
        float* tav = (float*)(wsb + (size_t)9 * NPIX * 8);
        float* fcA = (float*)(wsb + (size_t)9 * NPIX * 8 + (size_t)9 * NPIX * 4);
        float* fcB = fcA + NPIX;

        conv_fused<<<nblocks, 256, 0, stream>>>(guidance, conv_w, conv_b, aff_scale,
                                                feat_init, confidence,
                                                offset, affout, scale_out,
                                                tp, tav, fcA);

        float* fcIn = fcA;
        float* fcOut = fcB;
        for (int t = 0; t < 18; ++t) {
            float* cur = feats + (size_t)t * NPIX;
            prop2<<<nblocks, 256, 0, stream>>>(fcIn, confidence, tp, tav, cur,
                                               (t == 17) ? nullptr : fcOut,
                                               (t == 17) ? feat_final : nullptr);
            float* tmpp = fcIn; fcIn = fcOut; fcOut = tmpp;
        }
    } else {
        conv_fused<<<nblocks, 256, 0, stream>>>(guidance, conv_w, conv_b, aff_scale,
                                                feat_init, confidence,
                                                offset, affout, scale_out,
                                                nullptr, nullptr, nullptr);
        const float* prev = feat_init;
        for (int t = 0; t < 18; ++t) {
            float* cur = feats + (size_t)t * NPIX;
            prop<<<nblocks, 256, 0, stream>>>(prev, confidence, offset, affout, cur,
                                              (t == 17) ? feat_final : nullptr);
            prev = cur;
        }
    }
}